// Round 1
// baseline (1414.758 us; speedup 1.0000x reference)
//
#include <hip/hip_runtime.h>
#include <stdint.h>

typedef unsigned short u16;
typedef float floatx4 __attribute__((ext_vector_type(4)));
typedef short bf16x8 __attribute__((ext_vector_type(8)));

#define DEVI __device__ __forceinline__

#define B_ 2
#define L_ 2048
#define D_ 2048
#define H_ 16
#define HD_ 128
#define M_ 4096   // B*L

DEVI u16 f2bf(float f) {
  union { float f; uint32_t u; } v; v.f = f;
  uint32_t r = v.u + 0x7fffu + ((v.u >> 16) & 1u);
  return (u16)(r >> 16);
}
DEVI float bf2f(u16 h) {
  union { uint32_t u; float f; } v; v.u = ((uint32_t)h) << 16;
  return v.f;
}

DEVI floatx4 mfma16(bf16x8 a, bf16x8 b, floatx4 c) {
  return __builtin_amdgcn_mfma_f32_16x16x32_bf16(a, b, c, 0, 0, 0);
}

// ---------------- RMSNorm: fp32 row -> bf16 row (x * rsqrt(mean(x^2)+eps) * g)
__global__ void rmsnorm_kernel(const float* __restrict__ x, const float* __restrict__ g,
                               u16* __restrict__ out) {
  int row = blockIdx.x;
  int tid = threadIdx.x;
  const float* xr = x + (size_t)row * D_;
  float4 v0 = ((const float4*)xr)[tid];
  float4 v1 = ((const float4*)xr)[256 + tid];
  float ss = v0.x*v0.x + v0.y*v0.y + v0.z*v0.z + v0.w*v0.w
           + v1.x*v1.x + v1.y*v1.y + v1.z*v1.z + v1.w*v1.w;
  #pragma unroll
  for (int off = 32; off > 0; off >>= 1) ss += __shfl_xor(ss, off, 64);
  __shared__ float red[4];
  int wv = tid >> 6, ln = tid & 63;
  if (ln == 0) red[wv] = ss;
  __syncthreads();
  float tot = red[0] + red[1] + red[2] + red[3];
  float scale = rsqrtf(tot * (1.0f / (float)D_) + 1e-8f);
  float4 g0 = ((const float4*)g)[tid];
  float4 g1v = ((const float4*)g)[256 + tid];
  u16* orow = out + (size_t)row * D_;
  ushort4 o0, o1;
  o0.x = f2bf(v0.x * scale * g0.x);  o0.y = f2bf(v0.y * scale * g0.y);
  o0.z = f2bf(v0.z * scale * g0.z);  o0.w = f2bf(v0.w * scale * g0.w);
  o1.x = f2bf(v1.x * scale * g1v.x); o1.y = f2bf(v1.y * scale * g1v.y);
  o1.z = f2bf(v1.z * scale * g1v.z); o1.w = f2bf(v1.w * scale * g1v.w);
  ((ushort4*)orow)[tid] = o0;
  ((ushort4*)orow)[256 + tid] = o1;
}

// ---------------- Weight transpose+convert: fp32 W[K][N] -> bf16 Wt[N][K]
__global__ void transpose_w_kernel(const float* __restrict__ W, u16* __restrict__ Wt,
                                   int Kd, int Nd) {
  __shared__ float tile[32][33];
  int n0 = blockIdx.x * 32, k0 = blockIdx.y * 32;
  int tid = threadIdx.x;
  int r = tid >> 3, c4 = (tid & 7) * 4;
  float4 v = *(const float4*)(W + (size_t)(k0 + r) * Nd + n0 + c4);
  tile[r][c4 + 0] = v.x; tile[r][c4 + 1] = v.y; tile[r][c4 + 2] = v.z; tile[r][c4 + 3] = v.w;
  __syncthreads();
  ushort4 o;
  o.x = f2bf(tile[c4 + 0][r]); o.y = f2bf(tile[c4 + 1][r]);
  o.z = f2bf(tile[c4 + 2][r]); o.w = f2bf(tile[c4 + 3][r]);
  *(ushort4*)(Wt + (size_t)(n0 + r) * Kd + k0 + c4) = o;
}

// ---------------- RoPE on q,k from fused qkv; writes [B,H,L,HD] bf16
__global__ void rope_qk_kernel(const u16* __restrict__ qkv, u16* __restrict__ q_r,
                               u16* __restrict__ k_r) {
  int idx = blockIdx.x * 256 + threadIdx.x;      // ((b*L + l)*H + h)*64 + i
  int i = idx & 63;
  int h = (idx >> 6) & (H_ - 1);
  int l = (idx >> 10) & (L_ - 1);
  int b = idx >> 21;
  // inv_freq = 10000^(-i/64) = exp(-i * ln(10000)/64)
  float freq = expf(-(float)i * 0.14391156831212787f);
  float ang = (float)l * freq;
  float s, c;
  sincosf(ang, &s, &c);
  size_t base_in = (size_t)(b * L_ + l) * (3 * D_);
  size_t qi = base_in + h * HD_ + i;
  size_t ki = base_in + D_ + h * HD_ + i;
  float q1 = bf2f(qkv[qi]), q2 = bf2f(qkv[qi + 64]);
  float k1 = bf2f(qkv[ki]), k2 = bf2f(qkv[ki + 64]);
  size_t base_out = ((size_t)(b * H_ + h) * L_ + l) * HD_ + i;
  q_r[base_out]      = f2bf(q1 * c - q2 * s);
  q_r[base_out + 64] = f2bf(q2 * c + q1 * s);
  k_r[base_out]      = f2bf(k1 * c - k2 * s);
  k_r[base_out + 64] = f2bf(k2 * c + k1 * s);
}

// ---------------- V transpose: qkv v-part [B,L,H,HD] -> vt [B,H,HD,L] bf16
__global__ void v_transpose_kernel(const u16* __restrict__ qkv, u16* __restrict__ vt) {
  __shared__ u16 tile[32][36];
  int bh = blockIdx.z;
  int d0 = blockIdx.y * 32;
  int l0 = blockIdx.x * 32;
  int b = bh >> 4, h = bh & 15;
  int tid = threadIdx.x;
  int r = tid >> 3, c4 = (tid & 7) * 4;
  const u16* src = qkv + (size_t)(b * L_ + l0 + r) * (3 * D_) + 2 * D_ + h * HD_ + d0 + c4;
  ushort4 v = *(const ushort4*)src;
  tile[r][c4 + 0] = v.x; tile[r][c4 + 1] = v.y; tile[r][c4 + 2] = v.z; tile[r][c4 + 3] = v.w;
  __syncthreads();
  ushort4 o;
  o.x = tile[c4 + 0][r]; o.y = tile[c4 + 1][r]; o.z = tile[c4 + 2][r]; o.w = tile[c4 + 3][r];
  *(ushort4*)(vt + ((size_t)bh * HD_ + d0 + r) * L_ + l0 + c4) = o;
}

// ---------------- GEMM: C[M,N] = A[M,K](bf16) * Bt[N,K]^T(bf16) + bias, fused epilogues
// MODE 0: out bf16 = acc + bias
// MODE 1: out fp32 = acc + bias + resid (fp32)
// MODE 2: out bf16 = silu(gate) * (acc + bias)   (gate bf16 same shape)
template <int MODE>
__launch_bounds__(256, 2)
__global__ void gemm_bt_kernel(const u16* __restrict__ A, const u16* __restrict__ Bt,
                               const float* __restrict__ bias,
                               const float* __restrict__ resid, const u16* __restrict__ gate,
                               void* __restrict__ out, int Nn, int Kk) {
  __shared__ __attribute__((aligned(16))) u16 As[128 * 32];
  __shared__ __attribute__((aligned(16))) u16 Bs[128 * 32];
  int tid = threadIdx.x;
  int wave = tid >> 6, lane = tid & 63, quad = lane >> 4, lr = lane & 15;
  int m0 = blockIdx.y * 128, n0 = blockIdx.x * 128;
  int wm = (wave >> 1) * 64, wn = (wave & 1) * 64;
  floatx4 acc[4][4];
  floatx4 z4 = {0.f, 0.f, 0.f, 0.f};
  #pragma unroll
  for (int i = 0; i < 4; i++)
    #pragma unroll
    for (int j = 0; j < 4; j++) acc[i][j] = z4;
  int sr = tid >> 2, sc = (tid & 3) * 8;  // staging row / col(elem)
  const u16* Ap = A + (size_t)m0 * Kk;
  const u16* Bp = Bt + (size_t)n0 * Kk;
  for (int kt = 0; kt < Kk; kt += 32) {
    uint4 a0 = *(const uint4*)(Ap + (size_t)sr * Kk + kt + sc);
    uint4 a1 = *(const uint4*)(Ap + (size_t)(sr + 64) * Kk + kt + sc);
    uint4 b0 = *(const uint4*)(Bp + (size_t)sr * Kk + kt + sc);
    uint4 b1 = *(const uint4*)(Bp + (size_t)(sr + 64) * Kk + kt + sc);
    __syncthreads();
    ((uint4*)As)[tid] = a0;
    ((uint4*)As)[256 + tid] = a1;
    ((uint4*)Bs)[tid] = b0;
    ((uint4*)Bs)[256 + tid] = b1;
    __syncthreads();
    bf16x8 af[4], bfr[4];
    #pragma unroll
    for (int i = 0; i < 4; i++)
      af[i] = *(const bf16x8*)&As[(wm + i * 16 + lr) * 32 + quad * 8];
    #pragma unroll
    for (int i = 0; i < 4; i++)
      bfr[i] = *(const bf16x8*)&Bs[(wn + i * 16 + lr) * 32 + quad * 8];
    #pragma unroll
    for (int mi = 0; mi < 4; mi++)
      #pragma unroll
      for (int ni = 0; ni < 4; ni++)
        acc[mi][ni] = mfma16(af[mi], bfr[ni], acc[mi][ni]);
  }
  // epilogue: C row = quad*4 + reg, col = lane&15 within each 16x16 tile
  #pragma unroll
  for (int mi = 0; mi < 4; mi++) {
    #pragma unroll
    for (int ni = 0; ni < 4; ni++) {
      int col = n0 + wn + ni * 16 + lr;
      float bcol = bias[col];
      #pragma unroll
      for (int r2 = 0; r2 < 4; r2++) {
        int row = m0 + wm + mi * 16 + quad * 4 + r2;
        float v = acc[mi][ni][r2] + bcol;
        size_t off = (size_t)row * Nn + col;
        if (MODE == 0) {
          ((u16*)out)[off] = f2bf(v);
        } else if (MODE == 1) {
          ((float*)out)[off] = v + resid[off];
        } else {
          float gv = bf2f(gate[off]);
          float sg = gv / (1.f + __expf(-gv));
          ((u16*)out)[off] = f2bf(sg * v);
        }
      }
    }
  }
}

// ---------------- Flash attention: causal, per-(b,h,qtile-128) block, 4 waves
// q_r,k_r: [B,H,L,HD] bf16 ; vt: [B,H,HD,L] bf16 ; o: [B,L,H,HD] bf16
__launch_bounds__(256, 2)
__global__ void attn_kernel(const u16* __restrict__ q_r, const u16* __restrict__ k_r,
                            const u16* __restrict__ vt, u16* __restrict__ o) {
  __shared__ __attribute__((aligned(16))) u16 KPs[128 * 128];  // K-tile, then aliased by P
  __shared__ __attribute__((aligned(16))) u16 Vs[128 * 128];   // Vt-tile [d][k_local]
  int bh = blockIdx.y, b = bh >> 4, h = bh & 15;
  int qt = blockIdx.x, q0 = qt * 128;
  int tid = threadIdx.x, wave = tid >> 6, lane = tid & 63, quad = lane >> 4, lr = lane & 15;
  int wq0 = wave * 32;  // this wave's 32 q-rows within tile
  const u16* Qp = q_r + (size_t)bh * L_ * HD_;
  const u16* Kp = k_r + (size_t)bh * L_ * HD_;
  const u16* Vtp = vt + (size_t)bh * HD_ * L_;
  const float scale = 0.08838834764831845f;  // 1/sqrt(128)
  // Q fragments in registers: [mi][kk]
  bf16x8 qf[2][4];
  #pragma unroll
  for (int mi = 0; mi < 2; mi++)
    #pragma unroll
    for (int kk = 0; kk < 4; kk++)
      qf[mi][kk] = *(const bf16x8*)(Qp + (size_t)(q0 + wq0 + mi * 16 + lr) * HD_ + kk * 32 + quad * 8);
  float mrun[2][4], lrun[2][4];
  floatx4 z4 = {0.f, 0.f, 0.f, 0.f};
  floatx4 oacc[2][8];
  #pragma unroll
  for (int mi = 0; mi < 2; mi++) {
    #pragma unroll
    for (int r2 = 0; r2 < 4; r2++) { mrun[mi][r2] = -__builtin_inff(); lrun[mi][r2] = 0.f; }
    #pragma unroll
    for (int di = 0; di < 8; di++) oacc[mi][di] = z4;
  }
  int srow = tid >> 4, scol = (tid & 15) * 8;
  for (int jt = 0; jt <= qt; ++jt) {
    uint4 kreg[8], vreg[8];
    #pragma unroll
    for (int p = 0; p < 8; ++p) {
      int r = p * 16 + srow;
      kreg[p] = *(const uint4*)(Kp + (size_t)(jt * 128 + r) * HD_ + scol);
      vreg[p] = *(const uint4*)(Vtp + (size_t)r * L_ + jt * 128 + scol);
    }
    __syncthreads();  // prior iteration's LDS reads all done
    #pragma unroll
    for (int p = 0; p < 8; ++p) {
      ((uint4*)KPs)[p * 256 + tid] = kreg[p];
      ((uint4*)Vs)[p * 256 + tid] = vreg[p];
    }
    __syncthreads();
    // S = Q @ K^T for this wave's 32 q-rows x 128 k-cols
    floatx4 sacc[2][8];
    #pragma unroll
    for (int mi = 0; mi < 2; mi++)
      #pragma unroll
      for (int ni = 0; ni < 8; ni++) sacc[mi][ni] = z4;
    #pragma unroll
    for (int kk = 0; kk < 4; ++kk) {
      bf16x8 kf[8];
      #pragma unroll
      for (int ni = 0; ni < 8; ++ni)
        kf[ni] = *(const bf16x8*)&KPs[(ni * 16 + lr) * 128 + kk * 32 + quad * 8];
      #pragma unroll
      for (int mi = 0; mi < 2; mi++)
        #pragma unroll
        for (int ni = 0; ni < 8; ni++)
          sacc[mi][ni] = mfma16(qf[mi][kk], kf[ni], sacc[mi][ni]);
    }
    __syncthreads();  // everyone done reading K-tile; KPs becomes P
    bool diag = (jt == qt);
    #pragma unroll
    for (int mi = 0; mi < 2; mi++) {
      #pragma unroll
      for (int r2 = 0; r2 < 4; r2++) {
        int row_abs = q0 + wq0 + mi * 16 + quad * 4 + r2;
        float sv[8];
        float mloc = -__builtin_inff();
        #pragma unroll
        for (int ni = 0; ni < 8; ni++) {
          float v = sacc[mi][ni][r2] * scale;
          if (diag && (jt * 128 + ni * 16 + lr) > row_abs) v = -__builtin_inff();
          sv[ni] = v;
          mloc = fmaxf(mloc, v);
        }
        #pragma unroll
        for (int off = 1; off < 16; off <<= 1) mloc = fmaxf(mloc, __shfl_xor(mloc, off, 16));
        float mold = mrun[mi][r2];
        float mnew = fmaxf(mold, mloc);
        float alpha = __expf(mold - mnew);  // -inf -> 0
        float ls = 0.f;
        #pragma unroll
        for (int ni = 0; ni < 8; ni++) {
          float p = __expf(sv[ni] - mnew);  // -inf -> 0
          ls += p;
          KPs[(wq0 + mi * 16 + quad * 4 + r2) * 128 + ni * 16 + lr] = f2bf(p);
        }
        #pragma unroll
        for (int off = 1; off < 16; off <<= 1) ls += __shfl_xor(ls, off, 16);
        lrun[mi][r2] = lrun[mi][r2] * alpha + ls;
        mrun[mi][r2] = mnew;
        #pragma unroll
        for (int di = 0; di < 8; di++) oacc[mi][di][r2] *= alpha;
      }
    }
    __syncthreads();  // P writes drained (same-wave rows, but keep it safe)
    // O += P @ V   (A = P rows of this wave; B-frag from Vs[d][k] contiguous)
    #pragma unroll
    for (int kk = 0; kk < 4; ++kk) {
      bf16x8 pf[2], vf[8];
      #pragma unroll
      for (int mi = 0; mi < 2; mi++)
        pf[mi] = *(const bf16x8*)&KPs[(wq0 + mi * 16 + lr) * 128 + kk * 32 + quad * 8];
      #pragma unroll
      for (int di = 0; di < 8; di++)
        vf[di] = *(const bf16x8*)&Vs[(di * 16 + lr) * 128 + kk * 32 + quad * 8];
      #pragma unroll
      for (int mi = 0; mi < 2; mi++)
        #pragma unroll
        for (int di = 0; di < 8; di++)
          oacc[mi][di] = mfma16(pf[mi], vf[di], oacc[mi][di]);
    }
  }
  // epilogue: o[b, l, h, hd] = oacc / l
  #pragma unroll
  for (int mi = 0; mi < 2; mi++) {
    #pragma unroll
    for (int r2 = 0; r2 < 4; r2++) {
      float inv = 1.f / lrun[mi][r2];
      int l_abs = q0 + wq0 + mi * 16 + quad * 4 + r2;
      size_t base = (size_t)(b * L_ + l_abs) * D_ + h * HD_;
      #pragma unroll
      for (int di = 0; di < 8; di++)
        o[base + di * 16 + lr] = f2bf(oacc[mi][di][r2] * inv);
    }
  }
}

extern "C" void kernel_launch(void* const* d_in, const int* in_sizes, int n_in,
                              void* d_out, int out_size, void* d_ws, size_t ws_size,
                              hipStream_t stream) {
  const float* x    = (const float*)d_in[0];
  const float* Wqkv = (const float*)d_in[1];
  const float* bqkv = (const float*)d_in[2];
  const float* Wo   = (const float*)d_in[3];
  const float* bo   = (const float*)d_in[4];
  const float* g1   = (const float*)d_in[5];
  const float* g2   = (const float*)d_in[6];
  const float* Wp   = (const float*)d_in[7];
  const float* bp   = (const float*)d_in[8];
  const float* Wff  = (const float*)d_in[9];
  const float* bff  = (const float*)d_in[10];
  char* ws = (char*)d_ws;
  // layout (bytes): wbuf 64MB | h 16MB | x1 32MB | regionA 128MB  => 251,658,240 total
  u16*  wbuf = (u16*)(ws);
  u16*  hbuf = (u16*)(ws + 67108864);
  float* x1  = (float*)(ws + 83886080);
  char* rA = ws + 117440512;
  u16* qkv  = (u16*)(rA);                 // [4096,6144] bf16 (50.3MB)
  u16* q_r  = (u16*)(rA + 50331648);      // [B,H,L,HD]
  u16* k_r  = (u16*)(rA + 67108864);
  u16* vtb  = (u16*)(rA + 83886080);      // [B,H,HD,L]
  u16* ob   = (u16*)(rA + 100663296);     // [B,L,H,HD] = [4096,2048]
  u16* gate = (u16*)(rA);                 // reuse after attention
  u16* ffin = (u16*)(rA + 67108864);
  float* outp = (float*)d_out;
  dim3 blk(256);

  // 1. h = rms(x)*g1 (bf16)
  rmsnorm_kernel<<<M_, blk, 0, stream>>>(x, g1, hbuf);
  // 2. Wqkv^T -> bf16
  transpose_w_kernel<<<dim3(6144 / 32, 2048 / 32), blk, 0, stream>>>(Wqkv, wbuf, 2048, 6144);
  // 3. qkv = h @ Wqkv + bqkv (bf16)
  gemm_bt_kernel<0><<<dim3(48, 32), blk, 0, stream>>>(hbuf, wbuf, bqkv, nullptr, nullptr, qkv, 6144, 2048);
  // 4. RoPE q,k -> [B,H,L,HD]
  rope_qk_kernel<<<(B_ * L_ * H_ * 64) / 256, blk, 0, stream>>>(qkv, q_r, k_r);
  // 5. v -> [B,H,HD,L]
  v_transpose_kernel<<<dim3(L_ / 32, HD_ / 32, B_ * H_), blk, 0, stream>>>(qkv, vtb);
  // 6. causal flash attention -> o [B,L,H,HD]
  attn_kernel<<<dim3(L_ / 128, B_ * H_), blk, 0, stream>>>(q_r, k_r, vtb, ob);
  // 7. Wo^T
  transpose_w_kernel<<<dim3(2048 / 32, 2048 / 32), blk, 0, stream>>>(Wo, wbuf, 2048, 2048);
  // 8. x1 = o @ Wo + bo + x (fp32)
  gemm_bt_kernel<1><<<dim3(16, 32), blk, 0, stream>>>(ob, wbuf, bo, x, nullptr, x1, 2048, 2048);
  // 9. h2 = rms(x1)*g2
  rmsnorm_kernel<<<M_, blk, 0, stream>>>(x1, g2, hbuf);
  // 10. Wp^T
  transpose_w_kernel<<<dim3(16384 / 32, 2048 / 32), blk, 0, stream>>>(Wp, wbuf, 2048, 16384);
  // 11. gate = h2 @ Wp[:, :8192] + bp[:8192] (bf16)
  gemm_bt_kernel<0><<<dim3(64, 32), blk, 0, stream>>>(hbuf, wbuf, bp, nullptr, nullptr, gate, 8192, 2048);
  // 12. ffin = silu(gate) * (h2 @ Wp[:, 8192:] + bp[8192:]) (bf16)
  gemm_bt_kernel<2><<<dim3(64, 32), blk, 0, stream>>>(hbuf, wbuf + (size_t)8192 * 2048, bp + 8192,
                                                      nullptr, gate, ffin, 8192, 2048);
  // 13. Wff^T
  transpose_w_kernel<<<dim3(2048 / 32, 8192 / 32), blk, 0, stream>>>(Wff, wbuf, 8192, 2048);
  // 14. out = ffin @ Wff_out + bff + x1 (fp32)
  gemm_bt_kernel<1><<<dim3(16, 32), blk, 0, stream>>>(ffin, wbuf, bff, x1, nullptr, outp, 2048, 8192);
}

// Round 2
// 1208.247 us; speedup vs baseline: 1.1709x; 1.1709x over previous
//
#include <hip/hip_runtime.h>
#include <stdint.h>

typedef unsigned short u16;
typedef float floatx4 __attribute__((ext_vector_type(4)));
typedef short bf16x8 __attribute__((ext_vector_type(8)));

#define DEVI __device__ __forceinline__

#define B_ 2
#define L_ 2048
#define D_ 2048
#define H_ 16
#define HD_ 128
#define M_ 4096   // B*L

DEVI u16 f2bf(float f) {
  union { float f; uint32_t u; } v; v.f = f;
  uint32_t r = v.u + 0x7fffu + ((v.u >> 16) & 1u);
  return (u16)(r >> 16);
}
DEVI float bf2f(u16 h) {
  union { uint32_t u; float f; } v; v.u = ((uint32_t)h) << 16;
  return v.f;
}

DEVI floatx4 mfma16(bf16x8 a, bf16x8 b, floatx4 c) {
  return __builtin_amdgcn_mfma_f32_16x16x32_bf16(a, b, c, 0, 0, 0);
}

// async global->LDS, 16B per lane. lds dst must be wave-uniform base + lane*16.
DEVI void gl2lds16(const u16* g, u16* l) {
  __builtin_amdgcn_global_load_lds((const __attribute__((address_space(1))) void*)g,
                                   (__attribute__((address_space(3))) void*)l, 16, 0, 0);
}

// ---------------- RMSNorm: fp32 row -> bf16 row (x * rsqrt(mean(x^2)+eps) * g)
__global__ void rmsnorm_kernel(const float* __restrict__ x, const float* __restrict__ g,
                               u16* __restrict__ out) {
  int row = blockIdx.x;
  int tid = threadIdx.x;
  const float* xr = x + (size_t)row * D_;
  float4 v0 = ((const float4*)xr)[tid];
  float4 v1 = ((const float4*)xr)[256 + tid];
  float ss = v0.x*v0.x + v0.y*v0.y + v0.z*v0.z + v0.w*v0.w
           + v1.x*v1.x + v1.y*v1.y + v1.z*v1.z + v1.w*v1.w;
  #pragma unroll
  for (int off = 32; off > 0; off >>= 1) ss += __shfl_xor(ss, off, 64);
  __shared__ float red[4];
  int wv = tid >> 6, ln = tid & 63;
  if (ln == 0) red[wv] = ss;
  __syncthreads();
  float tot = red[0] + red[1] + red[2] + red[3];
  float scale = rsqrtf(tot * (1.0f / (float)D_) + 1e-8f);
  float4 g0 = ((const float4*)g)[tid];
  float4 g1v = ((const float4*)g)[256 + tid];
  u16* orow = out + (size_t)row * D_;
  ushort4 o0, o1;
  o0.x = f2bf(v0.x * scale * g0.x);  o0.y = f2bf(v0.y * scale * g0.y);
  o0.z = f2bf(v0.z * scale * g0.z);  o0.w = f2bf(v0.w * scale * g0.w);
  o1.x = f2bf(v1.x * scale * g1v.x); o1.y = f2bf(v1.y * scale * g1v.y);
  o1.z = f2bf(v1.z * scale * g1v.z); o1.w = f2bf(v1.w * scale * g1v.w);
  ((ushort4*)orow)[tid] = o0;
  ((ushort4*)orow)[256 + tid] = o1;
}

// ---------------- Weight transpose+convert: fp32 W[K][N] -> bf16 Wt[N][K]
__global__ void transpose_w_kernel(const float* __restrict__ W, u16* __restrict__ Wt,
                                   int Kd, int Nd) {
  __shared__ float tile[32][33];
  int n0 = blockIdx.x * 32, k0 = blockIdx.y * 32;
  int tid = threadIdx.x;
  int r = tid >> 3, c4 = (tid & 7) * 4;
  float4 v = *(const float4*)(W + (size_t)(k0 + r) * Nd + n0 + c4);
  tile[r][c4 + 0] = v.x; tile[r][c4 + 1] = v.y; tile[r][c4 + 2] = v.z; tile[r][c4 + 3] = v.w;
  __syncthreads();
  ushort4 o;
  o.x = f2bf(tile[c4 + 0][r]); o.y = f2bf(tile[c4 + 1][r]);
  o.z = f2bf(tile[c4 + 2][r]); o.w = f2bf(tile[c4 + 3][r]);
  *(ushort4*)(Wt + (size_t)(n0 + r) * Kd + k0 + c4) = o;
}

// ---------------- RoPE on q,k from fused qkv; writes [B,H,L,HD] bf16
__global__ void rope_qk_kernel(const u16* __restrict__ qkv, u16* __restrict__ q_r,
                               u16* __restrict__ k_r) {
  int idx = blockIdx.x * 256 + threadIdx.x;      // ((b*L + l)*H + h)*64 + i
  int i = idx & 63;
  int h = (idx >> 6) & (H_ - 1);
  int l = (idx >> 10) & (L_ - 1);
  int b = idx >> 21;
  float freq = expf(-(float)i * 0.14391156831212787f);
  float ang = (float)l * freq;
  float s, c;
  sincosf(ang, &s, &c);
  size_t base_in = (size_t)(b * L_ + l) * (3 * D_);
  size_t qi = base_in + h * HD_ + i;
  size_t ki = base_in + D_ + h * HD_ + i;
  float q1 = bf2f(qkv[qi]), q2 = bf2f(qkv[qi + 64]);
  float k1 = bf2f(qkv[ki]), k2 = bf2f(qkv[ki + 64]);
  size_t base_out = ((size_t)(b * H_ + h) * L_ + l) * HD_ + i;
  q_r[base_out]      = f2bf(q1 * c - q2 * s);
  q_r[base_out + 64] = f2bf(q2 * c + q1 * s);
  k_r[base_out]      = f2bf(k1 * c - k2 * s);
  k_r[base_out + 64] = f2bf(k2 * c + k1 * s);
}

// ---------------- V transpose: qkv v-part [B,L,H,HD] -> vt [B,H,HD,L] bf16
__global__ void v_transpose_kernel(const u16* __restrict__ qkv, u16* __restrict__ vt) {
  __shared__ u16 tile[32][36];
  int bh = blockIdx.z;
  int d0 = blockIdx.y * 32;
  int l0 = blockIdx.x * 32;
  int b = bh >> 4, h = bh & 15;
  int tid = threadIdx.x;
  int r = tid >> 3, c4 = (tid & 7) * 4;
  const u16* src = qkv + (size_t)(b * L_ + l0 + r) * (3 * D_) + 2 * D_ + h * HD_ + d0 + c4;
  ushort4 v = *(const ushort4*)src;
  tile[r][c4 + 0] = v.x; tile[r][c4 + 1] = v.y; tile[r][c4 + 2] = v.z; tile[r][c4 + 3] = v.w;
  __syncthreads();
  ushort4 o;
  o.x = tile[c4 + 0][r]; o.y = tile[c4 + 1][r]; o.z = tile[c4 + 2][r]; o.w = tile[c4 + 3][r];
  *(ushort4*)(vt + ((size_t)bh * HD_ + d0 + r) * L_ + l0 + c4) = o;
}

// ---------------- GEMM: C[M,N] = A[M,K](bf16) * Bt[N,K]^T(bf16) + bias, fused epilogues
// m97-style: global_load_lds width-16 staging + granule-XOR swizzle (conflict-free frags)
// MODE 0: out bf16 = acc + bias
// MODE 1: out fp32 = acc + bias + resid (fp32)
// MODE 2: out bf16 = silu(gate) * (acc + bias)   (gate bf16 same shape)
template <int MODE>
__launch_bounds__(256, 3)
__global__ void gemm_bt_kernel(const u16* __restrict__ A, const u16* __restrict__ Bt,
                               const float* __restrict__ bias,
                               const float* __restrict__ resid, const u16* __restrict__ gate,
                               void* __restrict__ out, int Nn, int Kk) {
  // LDS tile 128 rows x 32 cols bf16; row = 64B = 4 granules of 16B.
  // logical granule g of row r lives at slot (g ^ ((r>>1)&3))  -> 2-way banks on frag reads
  __shared__ __attribute__((aligned(16))) u16 As[128 * 32];
  __shared__ __attribute__((aligned(16))) u16 Bs[128 * 32];
  int tid = threadIdx.x;
  int wave = tid >> 6, lane = tid & 63, quad = lane >> 4, lr = lane & 15;
  int m0 = blockIdx.y * 128, n0 = blockIdx.x * 128;
  int wm = (wave >> 1) * 64, wn = (wave & 1) * 64;
  floatx4 acc[4][4];
  floatx4 z4 = {0.f, 0.f, 0.f, 0.f};
  #pragma unroll
  for (int i = 0; i < 4; i++)
    #pragma unroll
    for (int j = 0; j < 4; j++) acc[i][j] = z4;
  // DMA fetch mapping: part p: row = p*64 + (tid>>2); slot = tid&3;
  // fetch logical granule g = slot ^ ((row>>1)&3)  (row>>1 &3 == (tid>>3)&3 for both parts)
  int drow = tid >> 2;
  int dcol = ((tid & 3) ^ ((drow >> 1) & 3)) * 8;   // element offset of fetched granule
  const u16* Ap = A + (size_t)m0 * Kk;
  const u16* Bp = Bt + (size_t)n0 * Kk;
  int sw = (quad ^ ((lr >> 1) & 3)) * 8;            // frag-read swizzled granule offset
  for (int kt = 0; kt < Kk; kt += 32) {
    __syncthreads();
    gl2lds16(Ap + (size_t)drow * Kk + kt + dcol,        As + tid * 8);
    gl2lds16(Ap + (size_t)(drow + 64) * Kk + kt + dcol, As + 2048 + tid * 8);
    gl2lds16(Bp + (size_t)drow * Kk + kt + dcol,        Bs + tid * 8);
    gl2lds16(Bp + (size_t)(drow + 64) * Kk + kt + dcol, Bs + 2048 + tid * 8);
    __syncthreads();
    bf16x8 af[4], bfr[4];
    #pragma unroll
    for (int i = 0; i < 4; i++)
      af[i] = *(const bf16x8*)&As[(wm + i * 16 + lr) * 32 + sw];
    #pragma unroll
    for (int i = 0; i < 4; i++)
      bfr[i] = *(const bf16x8*)&Bs[(wn + i * 16 + lr) * 32 + sw];
    #pragma unroll
    for (int mi = 0; mi < 4; mi++)
      #pragma unroll
      for (int ni = 0; ni < 4; ni++)
        acc[mi][ni] = mfma16(af[mi], bfr[ni], acc[mi][ni]);
  }
  // epilogue: C row = quad*4 + reg, col = lane&15 within each 16x16 tile
  #pragma unroll
  for (int mi = 0; mi < 4; mi++) {
    #pragma unroll
    for (int ni = 0; ni < 4; ni++) {
      int col = n0 + wn + ni * 16 + lr;
      float bcol = bias[col];
      #pragma unroll
      for (int r2 = 0; r2 < 4; r2++) {
        int row = m0 + wm + mi * 16 + quad * 4 + r2;
        float v = acc[mi][ni][r2] + bcol;
        size_t off = (size_t)row * Nn + col;
        if (MODE == 0) {
          ((u16*)out)[off] = f2bf(v);
        } else if (MODE == 1) {
          ((float*)out)[off] = v + resid[off];
        } else {
          float gv = bf2f(gate[off]);
          float sg = gv / (1.f + __expf(-gv));
          ((u16*)out)[off] = f2bf(sg * v);
        }
      }
    }
  }
}

// ---------------- Flash attention: causal, per-(b,h,qtile-128) block, 4 waves
// q_r,k_r: [B,H,L,HD] bf16 ; vt: [B,H,HD,L] bf16 ; o: [B,L,H,HD] bf16
// K/V/P tiles: 128x128 bf16, 16 granules/row; granule g of row r at slot (g ^ (r&15))
__launch_bounds__(256, 2)
__global__ void attn_kernel(const u16* __restrict__ q_r, const u16* __restrict__ k_r,
                            const u16* __restrict__ vt, u16* __restrict__ o) {
  __shared__ __attribute__((aligned(16))) u16 KPs[128 * 128];  // K-tile, then aliased by P
  __shared__ __attribute__((aligned(16))) u16 Vs[128 * 128];   // Vt-tile [d][k_local]
  int bh = blockIdx.y, b = bh >> 4, h = bh & 15;
  // work-balance swizzle: co-resident pairs (x, y) and (x, y+16) get qt x and 15-x
  int qt = (blockIdx.y < 16) ? blockIdx.x : (15 - blockIdx.x);
  int q0 = qt * 128;
  int tid = threadIdx.x, wave = tid >> 6, lane = tid & 63, quad = lane >> 4, lr = lane & 15;
  int wq0 = wave * 32;  // this wave's 32 q-rows within tile
  const u16* Qp = q_r + (size_t)bh * L_ * HD_;
  const u16* Kp = k_r + (size_t)bh * L_ * HD_;
  const u16* Vtp = vt + (size_t)bh * HD_ * L_;
  const float scale = 0.08838834764831845f;  // 1/sqrt(128)
  // Q fragments in registers: [mi][kk]
  bf16x8 qf[2][4];
  #pragma unroll
  for (int mi = 0; mi < 2; mi++)
    #pragma unroll
    for (int kk = 0; kk < 4; kk++)
      qf[mi][kk] = *(const bf16x8*)(Qp + (size_t)(q0 + wq0 + mi * 16 + lr) * HD_ + kk * 32 + quad * 8);
  float mrun[2][4], lrun[2][4];
  floatx4 z4 = {0.f, 0.f, 0.f, 0.f};
  floatx4 oacc[2][8];
  #pragma unroll
  for (int mi = 0; mi < 2; mi++) {
    #pragma unroll
    for (int r2 = 0; r2 < 4; r2++) { mrun[mi][r2] = -__builtin_inff(); lrun[mi][r2] = 0.f; }
    #pragma unroll
    for (int di = 0; di < 8; di++) oacc[mi][di] = z4;
  }
  // DMA mapping: issue p: row = p*16 + (tid>>4), slot = tid&15,
  // fetched logical granule g = slot ^ (row&15) = (tid&15) ^ (tid>>4)
  int dr = tid >> 4;
  int dgo = ((tid & 15) ^ dr) * 8;   // element offset of fetched granule within row
  for (int jt = 0; jt <= qt; ++jt) {
    __syncthreads();  // prior iteration's LDS consumers all done
    #pragma unroll
    for (int p = 0; p < 8; ++p) {
      int r = p * 16 + dr;
      gl2lds16(Kp + (size_t)(jt * 128 + r) * HD_ + dgo, KPs + p * 2048 + tid * 8);
      gl2lds16(Vtp + (size_t)r * L_ + jt * 128 + dgo,   Vs + p * 2048 + tid * 8);
    }
    __syncthreads();  // DMA complete, visible to all waves
    // S = Q @ K^T for this wave's 32 q-rows x 128 k-cols
    floatx4 sacc[2][8];
    #pragma unroll
    for (int mi = 0; mi < 2; mi++)
      #pragma unroll
      for (int ni = 0; ni < 8; ni++) sacc[mi][ni] = z4;
    #pragma unroll
    for (int kk = 0; kk < 4; ++kk) {
      bf16x8 kf[8];
      #pragma unroll
      for (int ni = 0; ni < 8; ++ni)
        kf[ni] = *(const bf16x8*)&KPs[(ni * 16 + lr) * 128 + ((kk * 4 + quad) ^ lr) * 8];
      #pragma unroll
      for (int mi = 0; mi < 2; mi++)
        #pragma unroll
        for (int ni = 0; ni < 8; ni++)
          sacc[mi][ni] = mfma16(qf[mi][kk], kf[ni], sacc[mi][ni]);
    }
    __syncthreads();  // everyone done reading K-tile; KPs becomes P
    bool diag = (jt == qt);
    #pragma unroll
    for (int mi = 0; mi < 2; mi++) {
      #pragma unroll
      for (int r2 = 0; r2 < 4; r2++) {
        int row_abs = q0 + wq0 + mi * 16 + quad * 4 + r2;
        int prow = wq0 + mi * 16 + quad * 4 + r2;
        float sv[8];
        float mloc = -__builtin_inff();
        #pragma unroll
        for (int ni = 0; ni < 8; ni++) {
          float v = sacc[mi][ni][r2] * scale;
          if (diag && (jt * 128 + ni * 16 + lr) > row_abs) v = -__builtin_inff();
          sv[ni] = v;
          mloc = fmaxf(mloc, v);
        }
        #pragma unroll
        for (int off = 1; off < 16; off <<= 1) mloc = fmaxf(mloc, __shfl_xor(mloc, off, 16));
        float mold = mrun[mi][r2];
        float mnew = fmaxf(mold, mloc);
        float alpha = __expf(mold - mnew);  // -inf -> 0
        float ls = 0.f;
        #pragma unroll
        for (int ni = 0; ni < 8; ni++) {
          float p = __expf(sv[ni] - mnew);  // -inf -> 0
          ls += p;
          int slot = (ni * 2 + (lr >> 3)) ^ (prow & 15);
          KPs[prow * 128 + slot * 8 + (lr & 7)] = f2bf(p);
        }
        #pragma unroll
        for (int off = 1; off < 16; off <<= 1) ls += __shfl_xor(ls, off, 16);
        lrun[mi][r2] = lrun[mi][r2] * alpha + ls;
        mrun[mi][r2] = mnew;
        #pragma unroll
        for (int di = 0; di < 8; di++) oacc[mi][di][r2] *= alpha;
      }
    }
    // no barrier: P rows written & read by the SAME wave (compiler orders LDS ops)
    #pragma unroll
    for (int kk = 0; kk < 4; ++kk) {
      bf16x8 pf[2], vf[8];
      #pragma unroll
      for (int mi = 0; mi < 2; mi++)
        pf[mi] = *(const bf16x8*)&KPs[(wq0 + mi * 16 + lr) * 128 + ((kk * 4 + quad) ^ lr) * 8];
      #pragma unroll
      for (int di = 0; di < 8; di++)
        vf[di] = *(const bf16x8*)&Vs[(di * 16 + lr) * 128 + ((kk * 4 + quad) ^ lr) * 8];
      #pragma unroll
      for (int mi = 0; mi < 2; mi++)
        #pragma unroll
        for (int di = 0; di < 8; di++)
          oacc[mi][di] = mfma16(pf[mi], vf[di], oacc[mi][di]);
    }
  }
  // epilogue: o[b, l, h, hd] = oacc / l
  #pragma unroll
  for (int mi = 0; mi < 2; mi++) {
    #pragma unroll
    for (int r2 = 0; r2 < 4; r2++) {
      float inv = 1.f / lrun[mi][r2];
      int l_abs = q0 + wq0 + mi * 16 + quad * 4 + r2;
      size_t base = (size_t)(b * L_ + l_abs) * D_ + h * HD_;
      #pragma unroll
      for (int di = 0; di < 8; di++)
        o[base + di * 16 + lr] = f2bf(oacc[mi][di][r2] * inv);
    }
  }
}

extern "C" void kernel_launch(void* const* d_in, const int* in_sizes, int n_in,
                              void* d_out, int out_size, void* d_ws, size_t ws_size,
                              hipStream_t stream) {
  const float* x    = (const float*)d_in[0];
  const float* Wqkv = (const float*)d_in[1];
  const float* bqkv = (const float*)d_in[2];
  const float* Wo   = (const float*)d_in[3];
  const float* bo   = (const float*)d_in[4];
  const float* g1   = (const float*)d_in[5];
  const float* g2   = (const float*)d_in[6];
  const float* Wp   = (const float*)d_in[7];
  const float* bp   = (const float*)d_in[8];
  const float* Wff  = (const float*)d_in[9];
  const float* bff  = (const float*)d_in[10];
  char* ws = (char*)d_ws;
  // layout (bytes): wbuf 64MB | h 16MB | x1 32MB | regionA 128MB
  u16*  wbuf = (u16*)(ws);
  u16*  hbuf = (u16*)(ws + 67108864);
  float* x1  = (float*)(ws + 83886080);
  char* rA = ws + 117440512;
  u16* qkv  = (u16*)(rA);                 // [4096,6144] bf16 (50.3MB)
  u16* q_r  = (u16*)(rA + 50331648);      // [B,H,L,HD]
  u16* k_r  = (u16*)(rA + 67108864);
  u16* vtb  = (u16*)(rA + 83886080);      // [B,H,HD,L]
  u16* ob   = (u16*)(rA + 100663296);     // [B,L,H,HD] = [4096,2048]
  u16* gate = (u16*)(rA);                 // reuse after attention
  u16* ffin = (u16*)(rA + 67108864);
  float* outp = (float*)d_out;
  dim3 blk(256);

  // 1. h = rms(x)*g1 (bf16)
  rmsnorm_kernel<<<M_, blk, 0, stream>>>(x, g1, hbuf);
  // 2. Wqkv^T -> bf16
  transpose_w_kernel<<<dim3(6144 / 32, 2048 / 32), blk, 0, stream>>>(Wqkv, wbuf, 2048, 6144);
  // 3. qkv = h @ Wqkv + bqkv (bf16)
  gemm_bt_kernel<0><<<dim3(48, 32), blk, 0, stream>>>(hbuf, wbuf, bqkv, nullptr, nullptr, qkv, 6144, 2048);
  // 4. RoPE q,k -> [B,H,L,HD]
  rope_qk_kernel<<<(B_ * L_ * H_ * 64) / 256, blk, 0, stream>>>(qkv, q_r, k_r);
  // 5. v -> [B,H,HD,L]
  v_transpose_kernel<<<dim3(L_ / 32, HD_ / 32, B_ * H_), blk, 0, stream>>>(qkv, vtb);
  // 6. causal flash attention -> o [B,L,H,HD]
  attn_kernel<<<dim3(L_ / 128, B_ * H_), blk, 0, stream>>>(q_r, k_r, vtb, ob);
  // 7. Wo^T
  transpose_w_kernel<<<dim3(2048 / 32, 2048 / 32), blk, 0, stream>>>(Wo, wbuf, 2048, 2048);
  // 8. x1 = o @ Wo + bo + x (fp32)
  gemm_bt_kernel<1><<<dim3(16, 32), blk, 0, stream>>>(ob, wbuf, bo, x, nullptr, x1, 2048, 2048);
  // 9. h2 = rms(x1)*g2
  rmsnorm_kernel<<<M_, blk, 0, stream>>>(x1, g2, hbuf);
  // 10. Wp^T
  transpose_w_kernel<<<dim3(16384 / 32, 2048 / 32), blk, 0, stream>>>(Wp, wbuf, 2048, 16384);
  // 11. gate = h2 @ Wp[:, :8192] + bp[:8192] (bf16)
  gemm_bt_kernel<0><<<dim3(64, 32), blk, 0, stream>>>(hbuf, wbuf, bp, nullptr, nullptr, gate, 8192, 2048);
  // 12. ffin = silu(gate) * (h2 @ Wp[:, 8192:] + bp[8192:]) (bf16)
  gemm_bt_kernel<2><<<dim3(64, 32), blk, 0, stream>>>(hbuf, wbuf + (size_t)8192 * 2048, bp + 8192,
                                                      nullptr, gate, ffin, 8192, 2048);
  // 13. Wff^T
  transpose_w_kernel<<<dim3(2048 / 32, 8192 / 32), blk, 0, stream>>>(Wff, wbuf, 8192, 2048);
  // 14. out = ffin @ Wff_out + bff + x1 (fp32)
  gemm_bt_kernel<1><<<dim3(16, 32), blk, 0, stream>>>(ffin, wbuf, bff, x1, nullptr, outp, 2048, 8192);
}

// Round 3
// 1068.125 us; speedup vs baseline: 1.3245x; 1.1312x over previous
//
#include <hip/hip_runtime.h>
#include <stdint.h>

typedef unsigned short u16;
typedef float floatx4 __attribute__((ext_vector_type(4)));
typedef short bf16x8 __attribute__((ext_vector_type(8)));

#define DEVI __device__ __forceinline__

#define B_ 2
#define L_ 2048
#define D_ 2048
#define H_ 16
#define HD_ 128
#define M_ 4096   // B*L

DEVI u16 f2bf(float f) {
  union { float f; uint32_t u; } v; v.f = f;
  uint32_t r = v.u + 0x7fffu + ((v.u >> 16) & 1u);
  return (u16)(r >> 16);
}
DEVI float bf2f(u16 h) {
  union { uint32_t u; float f; } v; v.u = ((uint32_t)h) << 16;
  return v.f;
}

DEVI floatx4 mfma16(bf16x8 a, bf16x8 b, floatx4 c) {
  return __builtin_amdgcn_mfma_f32_16x16x32_bf16(a, b, c, 0, 0, 0);
}

// async global->LDS, 16B per lane. lds dst must be wave-uniform base + lane*16.
DEVI void gl2lds16(const u16* g, u16* l) {
  __builtin_amdgcn_global_load_lds((const __attribute__((address_space(1))) void*)g,
                                   (__attribute__((address_space(3))) void*)l, 16, 0, 0);
}

// ---------------- RMSNorm: fp32 row -> bf16 row (x * rsqrt(mean(x^2)+eps) * g)
__global__ void rmsnorm_kernel(const float* __restrict__ x, const float* __restrict__ g,
                               u16* __restrict__ out) {
  int row = blockIdx.x;
  int tid = threadIdx.x;
  const float* xr = x + (size_t)row * D_;
  float4 v0 = ((const float4*)xr)[tid];
  float4 v1 = ((const float4*)xr)[256 + tid];
  float ss = v0.x*v0.x + v0.y*v0.y + v0.z*v0.z + v0.w*v0.w
           + v1.x*v1.x + v1.y*v1.y + v1.z*v1.z + v1.w*v1.w;
  #pragma unroll
  for (int off = 32; off > 0; off >>= 1) ss += __shfl_xor(ss, off, 64);
  __shared__ float red[4];
  int wv = tid >> 6, ln = tid & 63;
  if (ln == 0) red[wv] = ss;
  __syncthreads();
  float tot = red[0] + red[1] + red[2] + red[3];
  float scale = rsqrtf(tot * (1.0f / (float)D_) + 1e-8f);
  float4 g0 = ((const float4*)g)[tid];
  float4 g1v = ((const float4*)g)[256 + tid];
  u16* orow = out + (size_t)row * D_;
  ushort4 o0, o1;
  o0.x = f2bf(v0.x * scale * g0.x);  o0.y = f2bf(v0.y * scale * g0.y);
  o0.z = f2bf(v0.z * scale * g0.z);  o0.w = f2bf(v0.w * scale * g0.w);
  o1.x = f2bf(v1.x * scale * g1v.x); o1.y = f2bf(v1.y * scale * g1v.y);
  o1.z = f2bf(v1.z * scale * g1v.z); o1.w = f2bf(v1.w * scale * g1v.w);
  ((ushort4*)orow)[tid] = o0;
  ((ushort4*)orow)[256 + tid] = o1;
}

// ---------------- Weight transpose+convert: fp32 W[K][N] -> bf16 Wt[N][K]
__global__ void transpose_w_kernel(const float* __restrict__ W, u16* __restrict__ Wt,
                                   int Kd, int Nd) {
  __shared__ float tile[32][33];
  int n0 = blockIdx.x * 32, k0 = blockIdx.y * 32;
  int tid = threadIdx.x;
  int r = tid >> 3, c4 = (tid & 7) * 4;
  float4 v = *(const float4*)(W + (size_t)(k0 + r) * Nd + n0 + c4);
  tile[r][c4 + 0] = v.x; tile[r][c4 + 1] = v.y; tile[r][c4 + 2] = v.z; tile[r][c4 + 3] = v.w;
  __syncthreads();
  ushort4 o;
  o.x = f2bf(tile[c4 + 0][r]); o.y = f2bf(tile[c4 + 1][r]);
  o.z = f2bf(tile[c4 + 2][r]); o.w = f2bf(tile[c4 + 3][r]);
  *(ushort4*)(Wt + (size_t)(n0 + r) * Kd + k0 + c4) = o;
}

// ---------------- RoPE on q,k from fused qkv; writes [B,H,L,HD] bf16
__global__ void rope_qk_kernel(const u16* __restrict__ qkv, u16* __restrict__ q_r,
                               u16* __restrict__ k_r) {
  int idx = blockIdx.x * 256 + threadIdx.x;      // ((b*L + l)*H + h)*64 + i
  int i = idx & 63;
  int h = (idx >> 6) & (H_ - 1);
  int l = (idx >> 10) & (L_ - 1);
  int b = idx >> 21;
  float freq = expf(-(float)i * 0.14391156831212787f);
  float ang = (float)l * freq;
  float s, c;
  sincosf(ang, &s, &c);
  size_t base_in = (size_t)(b * L_ + l) * (3 * D_);
  size_t qi = base_in + h * HD_ + i;
  size_t ki = base_in + D_ + h * HD_ + i;
  float q1 = bf2f(qkv[qi]), q2 = bf2f(qkv[qi + 64]);
  float k1 = bf2f(qkv[ki]), k2 = bf2f(qkv[ki + 64]);
  size_t base_out = ((size_t)(b * H_ + h) * L_ + l) * HD_ + i;
  q_r[base_out]      = f2bf(q1 * c - q2 * s);
  q_r[base_out + 64] = f2bf(q2 * c + q1 * s);
  k_r[base_out]      = f2bf(k1 * c - k2 * s);
  k_r[base_out + 64] = f2bf(k2 * c + k1 * s);
}

// ---------------- V transpose: qkv v-part [B,L,H,HD] -> vt [B,H,HD,L] bf16
__global__ void v_transpose_kernel(const u16* __restrict__ qkv, u16* __restrict__ vt) {
  __shared__ u16 tile[32][36];
  int bh = blockIdx.z;
  int d0 = blockIdx.y * 32;
  int l0 = blockIdx.x * 32;
  int b = bh >> 4, h = bh & 15;
  int tid = threadIdx.x;
  int r = tid >> 3, c4 = (tid & 7) * 4;
  const u16* src = qkv + (size_t)(b * L_ + l0 + r) * (3 * D_) + 2 * D_ + h * HD_ + d0 + c4;
  ushort4 v = *(const ushort4*)src;
  tile[r][c4 + 0] = v.x; tile[r][c4 + 1] = v.y; tile[r][c4 + 2] = v.z; tile[r][c4 + 3] = v.w;
  __syncthreads();
  ushort4 o;
  o.x = tile[c4 + 0][r]; o.y = tile[c4 + 1][r]; o.z = tile[c4 + 2][r]; o.w = tile[c4 + 3][r];
  *(ushort4*)(vt + ((size_t)bh * HD_ + d0 + r) * L_ + l0 + c4) = o;
}

// ======== BK=64 LDS tile helpers ========
// Tile: 128 rows x 64 cols bf16, row = 128B = 8 granules of 16B.
// Granule g of row r lives at slot (g ^ (r&7)) -> frag reads are 2-way (free).
// DMA part p (p=0..3): thread t -> row p*32 + (t>>3), fetches granule (t&7)^((t>>3)&7).

// ---------------- GEMM: C[M,N] = A[M,K](bf16) * Bt[N,K]^T(bf16) + bias, fused epilogues
// MODE 0: out bf16 = acc + bias
// MODE 1: out fp32 = acc + bias + resid (fp32)
template <int MODE>
__launch_bounds__(256, 3)
__global__ void gemm_bt_kernel(const u16* __restrict__ A, const u16* __restrict__ Bt,
                               const float* __restrict__ bias,
                               const float* __restrict__ resid,
                               void* __restrict__ out, int Nn, int Kk) {
  __shared__ __attribute__((aligned(16))) u16 As[128 * 64];
  __shared__ __attribute__((aligned(16))) u16 Bs[128 * 64];
  int tid = threadIdx.x;
  int wave = tid >> 6, lane = tid & 63, quad = lane >> 4, lr = lane & 15;
  int m0 = blockIdx.y * 128, n0 = blockIdx.x * 128;
  int wm = (wave >> 1) * 64, wn = (wave & 1) * 64;
  floatx4 acc[4][4];
  floatx4 z4 = {0.f, 0.f, 0.f, 0.f};
  #pragma unroll
  for (int i = 0; i < 4; i++)
    #pragma unroll
    for (int j = 0; j < 4; j++) acc[i][j] = z4;
  int dr8 = tid >> 3;                                // row within 32-row part
  int dg = ((tid & 7) ^ (dr8 & 7)) * 8;              // fetched granule elem offset
  const u16* Ap = A + (size_t)m0 * Kk;
  const u16* Bp = Bt + (size_t)n0 * Kk;
  for (int kt = 0; kt < Kk; kt += 64) {
    __syncthreads();
    #pragma unroll
    for (int p = 0; p < 4; p++)
      gl2lds16(Ap + (size_t)(p * 32 + dr8) * Kk + kt + dg, As + p * 2048 + tid * 8);
    #pragma unroll
    for (int p = 0; p < 4; p++)
      gl2lds16(Bp + (size_t)(p * 32 + dr8) * Kk + kt + dg, Bs + p * 2048 + tid * 8);
    __syncthreads();
    #pragma unroll
    for (int kk = 0; kk < 2; ++kk) {
      int swz = ((kk * 4 + quad) ^ (lr & 7)) * 8;
      bf16x8 af[4], bfr[4];
      #pragma unroll
      for (int i = 0; i < 4; i++)
        af[i] = *(const bf16x8*)&As[(wm + i * 16 + lr) * 64 + swz];
      #pragma unroll
      for (int i = 0; i < 4; i++)
        bfr[i] = *(const bf16x8*)&Bs[(wn + i * 16 + lr) * 64 + swz];
      #pragma unroll
      for (int mi = 0; mi < 4; mi++)
        #pragma unroll
        for (int ni = 0; ni < 4; ni++)
          acc[mi][ni] = mfma16(af[mi], bfr[ni], acc[mi][ni]);
    }
  }
  // epilogue: C row = quad*4 + reg, col = lane&15 within each 16x16 tile
  #pragma unroll
  for (int mi = 0; mi < 4; mi++) {
    #pragma unroll
    for (int ni = 0; ni < 4; ni++) {
      int col = n0 + wn + ni * 16 + lr;
      float bcol = bias[col];
      #pragma unroll
      for (int r2 = 0; r2 < 4; r2++) {
        int row = m0 + wm + mi * 16 + quad * 4 + r2;
        float v = acc[mi][ni][r2] + bcol;
        size_t off = (size_t)row * Nn + col;
        if (MODE == 0) {
          ((u16*)out)[off] = f2bf(v);
        } else {
          ((float*)out)[off] = v + resid[off];
        }
      }
    }
  }
}

// ---------------- Fused FFN-in GEMM: gate & value share A and output tile
// ffin[m, n] = silu(A@Wg^T + bg) * (A@Wv^T + bv), n in [0,8192)
__launch_bounds__(256, 2)
__global__ void ffn_gemm_kernel(const u16* __restrict__ A, const u16* __restrict__ Wt,
                                const float* __restrict__ bp,
                                u16* __restrict__ out, int Kk) {
  __shared__ __attribute__((aligned(16))) u16 As[128 * 64];
  __shared__ __attribute__((aligned(16))) u16 Bg[128 * 64];
  __shared__ __attribute__((aligned(16))) u16 Bv[128 * 64];
  int tid = threadIdx.x;
  int wave = tid >> 6, lane = tid & 63, quad = lane >> 4, lr = lane & 15;
  int m0 = blockIdx.y * 128, n0 = blockIdx.x * 128;
  int wm = (wave >> 1) * 64, wn = (wave & 1) * 64;
  floatx4 accg[4][4], accv[4][4];
  floatx4 z4 = {0.f, 0.f, 0.f, 0.f};
  #pragma unroll
  for (int i = 0; i < 4; i++)
    #pragma unroll
    for (int j = 0; j < 4; j++) { accg[i][j] = z4; accv[i][j] = z4; }
  int dr8 = tid >> 3;
  int dg = ((tid & 7) ^ (dr8 & 7)) * 8;
  const u16* Ap = A + (size_t)m0 * Kk;
  const u16* Bgp = Wt + (size_t)n0 * Kk;                    // gate rows [n0, n0+128)
  const u16* Bvp = Wt + (size_t)(8192 + n0) * Kk;           // value rows offset by 8192
  for (int kt = 0; kt < Kk; kt += 64) {
    __syncthreads();
    #pragma unroll
    for (int p = 0; p < 4; p++)
      gl2lds16(Ap + (size_t)(p * 32 + dr8) * Kk + kt + dg, As + p * 2048 + tid * 8);
    #pragma unroll
    for (int p = 0; p < 4; p++)
      gl2lds16(Bgp + (size_t)(p * 32 + dr8) * Kk + kt + dg, Bg + p * 2048 + tid * 8);
    #pragma unroll
    for (int p = 0; p < 4; p++)
      gl2lds16(Bvp + (size_t)(p * 32 + dr8) * Kk + kt + dg, Bv + p * 2048 + tid * 8);
    __syncthreads();
    #pragma unroll
    for (int kk = 0; kk < 2; ++kk) {
      int swz = ((kk * 4 + quad) ^ (lr & 7)) * 8;
      bf16x8 af[4], bgf[4], bvf[4];
      #pragma unroll
      for (int i = 0; i < 4; i++) {
        af[i]  = *(const bf16x8*)&As[(wm + i * 16 + lr) * 64 + swz];
        bgf[i] = *(const bf16x8*)&Bg[(wn + i * 16 + lr) * 64 + swz];
        bvf[i] = *(const bf16x8*)&Bv[(wn + i * 16 + lr) * 64 + swz];
      }
      #pragma unroll
      for (int mi = 0; mi < 4; mi++)
        #pragma unroll
        for (int ni = 0; ni < 4; ni++) {
          accg[mi][ni] = mfma16(af[mi], bgf[ni], accg[mi][ni]);
          accv[mi][ni] = mfma16(af[mi], bvf[ni], accv[mi][ni]);
        }
    }
  }
  #pragma unroll
  for (int mi = 0; mi < 4; mi++) {
    #pragma unroll
    for (int ni = 0; ni < 4; ni++) {
      int col = n0 + wn + ni * 16 + lr;
      float bg = bp[col], bv = bp[col + 8192];
      #pragma unroll
      for (int r2 = 0; r2 < 4; r2++) {
        int row = m0 + wm + mi * 16 + quad * 4 + r2;
        float gv = accg[mi][ni][r2] + bg;
        float vv = accv[mi][ni][r2] + bv;
        float sg = gv / (1.f + __expf(-gv));
        out[(size_t)row * 8192 + col] = f2bf(sg * vv);
      }
    }
  }
}

// ---------------- Flash attention: causal, per-(b,h,qtile-128) block, 4 waves
__launch_bounds__(256, 2)
__global__ void attn_kernel(const u16* __restrict__ q_r, const u16* __restrict__ k_r,
                            const u16* __restrict__ vt, u16* __restrict__ o) {
  __shared__ __attribute__((aligned(16))) u16 KPs[128 * 128];  // K-tile, then aliased by P
  __shared__ __attribute__((aligned(16))) u16 Vs[128 * 128];   // Vt-tile [d][k_local]
  int bh = blockIdx.y, b = bh >> 4, h = bh & 15;
  int qt = (blockIdx.y < 16) ? blockIdx.x : (15 - blockIdx.x);
  int q0 = qt * 128;
  int tid = threadIdx.x, wave = tid >> 6, lane = tid & 63, quad = lane >> 4, lr = lane & 15;
  int wq0 = wave * 32;
  const u16* Qp = q_r + (size_t)bh * L_ * HD_;
  const u16* Kp = k_r + (size_t)bh * L_ * HD_;
  const u16* Vtp = vt + (size_t)bh * HD_ * L_;
  const float scale = 0.08838834764831845f;  // 1/sqrt(128)
  bf16x8 qf[2][4];
  #pragma unroll
  for (int mi = 0; mi < 2; mi++)
    #pragma unroll
    for (int kk = 0; kk < 4; kk++)
      qf[mi][kk] = *(const bf16x8*)(Qp + (size_t)(q0 + wq0 + mi * 16 + lr) * HD_ + kk * 32 + quad * 8);
  float mrun[2][4], lrun[2][4];
  floatx4 z4 = {0.f, 0.f, 0.f, 0.f};
  floatx4 oacc[2][8];
  #pragma unroll
  for (int mi = 0; mi < 2; mi++) {
    #pragma unroll
    for (int r2 = 0; r2 < 4; r2++) { mrun[mi][r2] = -__builtin_inff(); lrun[mi][r2] = 0.f; }
    #pragma unroll
    for (int di = 0; di < 8; di++) oacc[mi][di] = z4;
  }
  int dr = tid >> 4;
  int dgo = ((tid & 15) ^ dr) * 8;
  for (int jt = 0; jt <= qt; ++jt) {
    __syncthreads();
    #pragma unroll
    for (int p = 0; p < 8; ++p) {
      int r = p * 16 + dr;
      gl2lds16(Kp + (size_t)(jt * 128 + r) * HD_ + dgo, KPs + p * 2048 + tid * 8);
      gl2lds16(Vtp + (size_t)r * L_ + jt * 128 + dgo,   Vs + p * 2048 + tid * 8);
    }
    __syncthreads();
    floatx4 sacc[2][8];
    #pragma unroll
    for (int mi = 0; mi < 2; mi++)
      #pragma unroll
      for (int ni = 0; ni < 8; ni++) sacc[mi][ni] = z4;
    #pragma unroll
    for (int kk = 0; kk < 4; ++kk) {
      bf16x8 kf[8];
      #pragma unroll
      for (int ni = 0; ni < 8; ++ni)
        kf[ni] = *(const bf16x8*)&KPs[(ni * 16 + lr) * 128 + ((kk * 4 + quad) ^ lr) * 8];
      #pragma unroll
      for (int mi = 0; mi < 2; mi++)
        #pragma unroll
        for (int ni = 0; ni < 8; ni++)
          sacc[mi][ni] = mfma16(qf[mi][kk], kf[ni], sacc[mi][ni]);
    }
    __syncthreads();
    bool diag = (jt == qt);
    #pragma unroll
    for (int mi = 0; mi < 2; mi++) {
      #pragma unroll
      for (int r2 = 0; r2 < 4; r2++) {
        int row_abs = q0 + wq0 + mi * 16 + quad * 4 + r2;
        int prow = wq0 + mi * 16 + quad * 4 + r2;
        float sv[8];
        float mloc = -__builtin_inff();
        #pragma unroll
        for (int ni = 0; ni < 8; ni++) {
          float v = sacc[mi][ni][r2] * scale;
          if (diag && (jt * 128 + ni * 16 + lr) > row_abs) v = -__builtin_inff();
          sv[ni] = v;
          mloc = fmaxf(mloc, v);
        }
        #pragma unroll
        for (int off = 1; off < 16; off <<= 1) mloc = fmaxf(mloc, __shfl_xor(mloc, off, 16));
        float mold = mrun[mi][r2];
        float mnew = fmaxf(mold, mloc);
        float alpha = __expf(mold - mnew);
        float ls = 0.f;
        #pragma unroll
        for (int ni = 0; ni < 8; ni++) {
          float p = __expf(sv[ni] - mnew);
          ls += p;
          int slot = (ni * 2 + (lr >> 3)) ^ (prow & 15);
          KPs[prow * 128 + slot * 8 + (lr & 7)] = f2bf(p);
        }
        #pragma unroll
        for (int off = 1; off < 16; off <<= 1) ls += __shfl_xor(ls, off, 16);
        lrun[mi][r2] = lrun[mi][r2] * alpha + ls;
        mrun[mi][r2] = mnew;
        #pragma unroll
        for (int di = 0; di < 8; di++) oacc[mi][di][r2] *= alpha;
      }
    }
    #pragma unroll
    for (int kk = 0; kk < 4; ++kk) {
      bf16x8 pf[2], vf[8];
      #pragma unroll
      for (int mi = 0; mi < 2; mi++)
        pf[mi] = *(const bf16x8*)&KPs[(wq0 + mi * 16 + lr) * 128 + ((kk * 4 + quad) ^ lr) * 8];
      #pragma unroll
      for (int di = 0; di < 8; di++)
        vf[di] = *(const bf16x8*)&Vs[(di * 16 + lr) * 128 + ((kk * 4 + quad) ^ lr) * 8];
      #pragma unroll
      for (int mi = 0; mi < 2; mi++)
        #pragma unroll
        for (int di = 0; di < 8; di++)
          oacc[mi][di] = mfma16(pf[mi], vf[di], oacc[mi][di]);
    }
  }
  #pragma unroll
  for (int mi = 0; mi < 2; mi++) {
    #pragma unroll
    for (int r2 = 0; r2 < 4; r2++) {
      float inv = 1.f / lrun[mi][r2];
      int l_abs = q0 + wq0 + mi * 16 + quad * 4 + r2;
      size_t base = (size_t)(b * L_ + l_abs) * D_ + h * HD_;
      #pragma unroll
      for (int di = 0; di < 8; di++)
        o[base + di * 16 + lr] = f2bf(oacc[mi][di][r2] * inv);
    }
  }
}

extern "C" void kernel_launch(void* const* d_in, const int* in_sizes, int n_in,
                              void* d_out, int out_size, void* d_ws, size_t ws_size,
                              hipStream_t stream) {
  const float* x    = (const float*)d_in[0];
  const float* Wqkv = (const float*)d_in[1];
  const float* bqkv = (const float*)d_in[2];
  const float* Wo   = (const float*)d_in[3];
  const float* bo   = (const float*)d_in[4];
  const float* g1   = (const float*)d_in[5];
  const float* g2   = (const float*)d_in[6];
  const float* Wp   = (const float*)d_in[7];
  const float* bp   = (const float*)d_in[8];
  const float* Wff  = (const float*)d_in[9];
  const float* bff  = (const float*)d_in[10];
  char* ws = (char*)d_ws;
  u16*  wbuf = (u16*)(ws);
  u16*  hbuf = (u16*)(ws + 67108864);
  float* x1  = (float*)(ws + 83886080);
  char* rA = ws + 117440512;
  u16* qkv  = (u16*)(rA);                 // [4096,6144] bf16
  u16* q_r  = (u16*)(rA + 50331648);      // [B,H,L,HD]
  u16* k_r  = (u16*)(rA + 67108864);
  u16* vtb  = (u16*)(rA + 83886080);      // [B,H,HD,L]
  u16* ob   = (u16*)(rA + 100663296);     // [B,L,H,HD] = [4096,2048]
  u16* ffin = (u16*)(rA);                 // [4096,8192] reuse after attention
  float* outp = (float*)d_out;
  dim3 blk(256);

  // 1. h = rms(x)*g1 (bf16)
  rmsnorm_kernel<<<M_, blk, 0, stream>>>(x, g1, hbuf);
  // 2. Wqkv^T -> bf16
  transpose_w_kernel<<<dim3(6144 / 32, 2048 / 32), blk, 0, stream>>>(Wqkv, wbuf, 2048, 6144);
  // 3. qkv = h @ Wqkv + bqkv (bf16)
  gemm_bt_kernel<0><<<dim3(48, 32), blk, 0, stream>>>(hbuf, wbuf, bqkv, nullptr, qkv, 6144, 2048);
  // 4. RoPE q,k -> [B,H,L,HD]
  rope_qk_kernel<<<(B_ * L_ * H_ * 64) / 256, blk, 0, stream>>>(qkv, q_r, k_r);
  // 5. v -> [B,H,HD,L]
  v_transpose_kernel<<<dim3(L_ / 32, HD_ / 32, B_ * H_), blk, 0, stream>>>(qkv, vtb);
  // 6. causal flash attention -> o [B,L,H,HD]
  attn_kernel<<<dim3(L_ / 128, B_ * H_), blk, 0, stream>>>(q_r, k_r, vtb, ob);
  // 7. Wo^T
  transpose_w_kernel<<<dim3(2048 / 32, 2048 / 32), blk, 0, stream>>>(Wo, wbuf, 2048, 2048);
  // 8. x1 = o @ Wo + bo + x (fp32)
  gemm_bt_kernel<1><<<dim3(16, 32), blk, 0, stream>>>(ob, wbuf, bo, x, x1, 2048, 2048);
  // 9. h2 = rms(x1)*g2
  rmsnorm_kernel<<<M_, blk, 0, stream>>>(x1, g2, hbuf);
  // 10. Wp^T
  transpose_w_kernel<<<dim3(16384 / 32, 2048 / 32), blk, 0, stream>>>(Wp, wbuf, 2048, 16384);
  // 11. ffin = silu(h2@Wg + bg) * (h2@Wv + bv)  (fused, bf16)
  ffn_gemm_kernel<<<dim3(64, 32), blk, 0, stream>>>(hbuf, wbuf, bp, ffin, 2048);
  // 12. Wff^T
  transpose_w_kernel<<<dim3(2048 / 32, 8192 / 32), blk, 0, stream>>>(Wff, wbuf, 8192, 2048);
  // 13. out = ffin @ Wff_out + bff + x1 (fp32)
  gemm_bt_kernel<1><<<dim3(16, 32), blk, 0, stream>>>(ffin, wbuf, bff, x1, outp, 2048, 8192);
}